// Round 6
// baseline (754.973 us; speedup 1.0000x reference)
//
#include <hip/hip_runtime.h>

#define N_NODES 50000
#define N_HEDGES 10000
#define DDIM 128

#define SCAN_BLK_ITEMS 4096  // 256 threads * 16 items
#define NXCD 8
#define BCAP 10240  // bucket cell capacity: mean 9375, sigma ~91 -> 9.5 sigma margin

// ---------------- phase 1: partition edges into per-(writer,owner) buckets ----
// Edge list is read ONCE. Each wave ballot-aggregates its 64 edges by owner
// group (8-way) and appends them to bucket cell [wg][og] with a single cursor
// atomic per group per wave. Cell [wg][og] is written ONLY by blocks with
// blockIdx&7==wg (one XCD under round-robin dispatch), sequentially -> cache
// lines fill completely before writeback. Degree histogram fused (plain
// device-scope atomics, low contention). Payloads: bktE holds (d,s), bktN (s,d).
__global__ __launch_bounds__(256) void partition_hist(
    const int* __restrict__ src, const int* __restrict__ dst, int nnz,
    int* __restrict__ degs,  // [deg_e | deg_n | pcurE(64) | pcurN(64)], zeroed
    int2* __restrict__ bktE, int2* __restrict__ bktN) {
  int* deg_e = degs;
  int* deg_n = degs + N_HEDGES;
  int* pcurE = degs + N_HEDGES + N_NODES;
  int* pcurN = pcurE + 64;
  const int wg = blockIdx.x & (NXCD - 1);
  const int lane = threadIdx.x & 63;
  const unsigned long long below = (1ull << lane) - 1;
  const int stride = gridDim.x * 256;
  // wave-uniform loop bound: i0 is the wave's base index
  for (int i0 = blockIdx.x * 256 + (threadIdx.x & ~63); i0 < nnz; i0 += stride) {
    int i = i0 + lane;
    bool v = i < nnz;
    int s = 0, d = 0;
    if (v) {
      s = src[i];
      d = dst[i];
      atomicAdd(&deg_e[d], 1);
      atomicAdd(&deg_n[s], 1);
    }
    int oge = v ? d / (N_HEDGES / NXCD) : -1;
    int ogn = v ? s / (N_NODES / NXCD) : -1;
#pragma unroll
    for (int k = 0; k < NXCD; ++k) {
      unsigned long long m = __ballot(oge == k);
      if (m) {
        int leader = __ffsll(m) - 1;
        int base = 0;
        if (lane == leader) base = atomicAdd(&pcurE[wg * NXCD + k], __popcll(m));
        base = __shfl(base, leader);
        if (oge == k) {
          int pos = base + __popcll(m & below);
          if (pos < BCAP) bktE[((size_t)(wg * NXCD + k)) * BCAP + pos] = make_int2(d, s);
        }
      }
    }
#pragma unroll
    for (int k = 0; k < NXCD; ++k) {
      unsigned long long m = __ballot(ogn == k);
      if (m) {
        int leader = __ffsll(m) - 1;
        int base = 0;
        if (lane == leader) base = atomicAdd(&pcurN[wg * NXCD + k], __popcll(m));
        base = __shfl(base, leader);
        if (ogn == k) {
          int pos = base + __popcll(m & below);
          if (pos < BCAP) bktN[((size_t)(wg * NXCD + k)) * BCAP + pos] = make_int2(s, d);
        }
      }
    }
  }
}

// ---------------- hierarchical scan, pass 1: per-block sums ----------------
__global__ __launch_bounds__(256) void scan_pass1(
    const int* __restrict__ deg_e, const int* __restrict__ deg_n,
    int* __restrict__ aux, int nb_e) {
  int b = blockIdx.x;
  const int* deg;
  int n, chunk;
  if (b < nb_e) { deg = deg_e; n = N_HEDGES; chunk = b; }
  else          { deg = deg_n; n = N_NODES;  chunk = b - nb_e; }
  int base = chunk * SCAN_BLK_ITEMS + threadIdx.x * 16;
  int s = 0;
  if (base + 16 <= n) {
    const int4* p = (const int4*)(deg + base);
#pragma unroll
    for (int i = 0; i < 4; ++i) { int4 v = p[i]; s += v.x + v.y + v.z + v.w; }
  } else {
    for (int i = 0; i < 16; ++i) { int idx = base + i; if (idx < n) s += deg[idx]; }
  }
  __shared__ int red[256];
  red[threadIdx.x] = s;
  __syncthreads();
  for (int o = 128; o > 0; o >>= 1) {
    if (threadIdx.x < o) red[threadIdx.x] += red[threadIdx.x + o];
    __syncthreads();
  }
  if (threadIdx.x == 0) aux[b] = red[0];
}

// ---------------- pass 2: serial exclusive scan of block sums (tiny) --------
__global__ __launch_bounds__(64) void scan_pass2(
    int* __restrict__ aux, int nb_e, int nb_tot,
    int* __restrict__ offs_e, int* __restrict__ offs_n, int n_e, int n_n) {
  if (threadIdx.x == 0) {
    int run = 0;
    for (int i = 0; i < nb_e; ++i) { int v = aux[i]; aux[i] = run; run += v; }
    offs_e[n_e] = run;
    run = 0;
    for (int i = nb_e; i < nb_tot; ++i) { int v = aux[i]; aux[i] = run; run += v; }
    offs_n[n_n] = run;
  }
}

// ---------------- pass 3: per-block exclusive scan + aux offset -------------
__global__ __launch_bounds__(256) void scan_pass3(
    const int* __restrict__ deg_e, const int* __restrict__ deg_n,
    const int* __restrict__ aux, int nb_e,
    int* __restrict__ offs_e, int* __restrict__ offs_n,
    int* __restrict__ cur_e, int* __restrict__ cur_n) {
  int b = blockIdx.x;
  const int* deg;
  int n, chunk;
  int *offs, *cur;
  if (b < nb_e) { deg = deg_e; n = N_HEDGES; chunk = b;        offs = offs_e; cur = cur_e; }
  else          { deg = deg_n; n = N_NODES;  chunk = b - nb_e; offs = offs_n; cur = cur_n; }
  int base = chunk * SCAN_BLK_ITEMS + threadIdx.x * 16;
  int v[16];
  int s = 0;
  bool full = (base + 16 <= n);
  if (full) {
    const int4* p = (const int4*)(deg + base);
#pragma unroll
    for (int i = 0; i < 4; ++i) {
      int4 q = p[i];
      v[4 * i] = q.x; v[4 * i + 1] = q.y; v[4 * i + 2] = q.z; v[4 * i + 3] = q.w;
    }
  } else {
    for (int i = 0; i < 16; ++i) { int idx = base + i; v[i] = (idx < n) ? deg[idx] : 0; }
  }
#pragma unroll
  for (int i = 0; i < 16; ++i) { int t = v[i]; v[i] = s; s += t; }
  __shared__ int red[256];
  int t = threadIdx.x;
  red[t] = s;
  __syncthreads();
  for (int o = 1; o < 256; o <<= 1) {
    int u = (t >= o) ? red[t - o] : 0;
    __syncthreads();
    red[t] += u;
    __syncthreads();
  }
  int pre = (t == 0) ? 0 : red[t - 1];
  pre += aux[b];
  if (full) {
#pragma unroll
    for (int i = 0; i < 16; ++i) v[i] += pre;
    int4* o4 = (int4*)(offs + base);
    int4* c4 = (int4*)(cur + base);
#pragma unroll
    for (int i = 0; i < 4; ++i) {
      int4 q = {v[4 * i], v[4 * i + 1], v[4 * i + 2], v[4 * i + 3]};
      o4[i] = q;
      c4[i] = q;
    }
  } else {
    for (int i = 0; i < 16; ++i) {
      int idx = base + i;
      if (idx < n) { offs[idx] = v[i] + pre; cur[idx] = v[i] + pre; }
    }
  }
}

// ---------------- phase 2: CSR fill from buckets (owner-local) --------------
// Block b: og = b&7 (owner), side = (b>>3)&1, sub = b>>4. Owner og reads the
// 8 cells [wg][og] (written cross-XCD once, ~600 KB) and scatters into its own
// adj/cursor slice, which is L2-resident with no competing stream.
#define FILL_SUB 32
__global__ __launch_bounds__(256) void fill_b(
    const int* __restrict__ cursors,  // [pcurE(64) | pcurN(64)]
    const int2* __restrict__ bktE, const int2* __restrict__ bktN,
    int* __restrict__ cur_e, int* __restrict__ cur_n,
    int* __restrict__ adj_e, int* __restrict__ adj_n) {
  int b = blockIdx.x;
  int og = b & 7;
  int side = (b >> 3) & 1;
  int sub = b >> 4;  // 0..FILL_SUB-1
  const int* curArr = cursors + (side ? 64 : 0);
  const int2* bkt = side ? bktN : bktE;
  int* cur = side ? cur_n : cur_e;
  int* adj = side ? adj_n : adj_e;
  for (int wg = 0; wg < NXCD; ++wg) {
    int cell = wg * NXCD + og;
    int cnt = min(curArr[cell], BCAP);
    const int2* p = bkt + (size_t)cell * BCAP;
    for (int idx = sub * 256 + (int)threadIdx.x; idx < cnt; idx += FILL_SUB * 256) {
      int2 e = p[idx];  // e.x = key, e.y = payload
      adj[atomicAdd(&cur[e.x], 1)] = e.y;
    }
  }
}

// ---------------- GEMM: Y[n_rows,128] = X[n_rows,128] * W[128,128] ----------
#define ACC4(accv, xv)                                          \
  accv.x += xv.x * w0.x + xv.y * w1.x + xv.z * w2.x + xv.w * w3.x; \
  accv.y += xv.x * w0.y + xv.y * w1.y + xv.z * w2.y + xv.w * w3.y; \
  accv.z += xv.x * w0.z + xv.y * w1.z + xv.z * w2.z + xv.w * w3.z; \
  accv.w += xv.x * w0.w + xv.y * w1.w + xv.z * w2.w + xv.w * w3.w;

__global__ __launch_bounds__(256, 2) void gemm128(
    const float* __restrict__ X, const float* __restrict__ W,
    float* __restrict__ Y, int n_rows) {
  __shared__ float sW[128 * 128];  // 64 KB
  __shared__ float sX[32 * 128];   // 16 KB
  const int t = threadIdx.x;
  {
    const float4* W4 = (const float4*)W;
    float4* sW4w = (float4*)sW;
#pragma unroll
    for (int i = 0; i < 16; ++i) sW4w[t + 256 * i] = W4[t + 256 * i];
  }
  const int lane = t & 63;
  const int wid = t >> 6;
  const int cg = lane & 31;                          // cols [4cg, 4cg+4)
  const int row_in_blk = wid * 8 + (lane >> 5) * 4;  // 4 rows per thread
  const float4* sW4 = (const float4*)sW;

  for (int base = blockIdx.x * 32; base < n_rows; base += gridDim.x * 32) {
    __syncthreads();
    {
      const float4* X4 = (const float4*)(X + (size_t)base * DDIM);
      float4* sX4 = (float4*)sX;
      int limit4 = min(32, n_rows - base) * 32;
#pragma unroll
      for (int i = 0; i < 4; ++i) {
        int idx = t + 256 * i;
        if (idx < limit4) sX4[idx] = X4[idx];
      }
    }
    __syncthreads();
    float4 acc0 = {0, 0, 0, 0}, acc1 = {0, 0, 0, 0}, acc2 = {0, 0, 0, 0}, acc3 = {0, 0, 0, 0};
    const float4* x0 = (const float4*)(sX + (row_in_blk + 0) * DDIM);
    const float4* x1 = (const float4*)(sX + (row_in_blk + 1) * DDIM);
    const float4* x2 = (const float4*)(sX + (row_in_blk + 2) * DDIM);
    const float4* x3 = (const float4*)(sX + (row_in_blk + 3) * DDIM);
#pragma unroll 8
    for (int k4 = 0; k4 < 32; ++k4) {
      float4 w0 = sW4[(4 * k4 + 0) * 32 + cg];
      float4 w1 = sW4[(4 * k4 + 1) * 32 + cg];
      float4 w2 = sW4[(4 * k4 + 2) * 32 + cg];
      float4 w3 = sW4[(4 * k4 + 3) * 32 + cg];
      float4 xa = x0[k4], xb = x1[k4], xc = x2[k4], xd = x3[k4];
      ACC4(acc0, xa)
      ACC4(acc1, xb)
      ACC4(acc2, xc)
      ACC4(acc3, xd)
    }
    int r = base + row_in_blk;
    if (r + 0 < n_rows) ((float4*)(Y + (size_t)(r + 0) * DDIM))[cg] = acc0;
    if (r + 1 < n_rows) ((float4*)(Y + (size_t)(r + 1) * DDIM))[cg] = acc1;
    if (r + 2 < n_rows) ((float4*)(Y + (size_t)(r + 2) * DDIM))[cg] = acc2;
    if (r + 3 < n_rows) ((float4*)(Y + (size_t)(r + 3) * DDIM))[cg] = acc3;
  }
}

// ---------------- segment mean, float4 half-wave (2 edges/iter, 4 in flight) -
// Half-wave h (lanes h*32..h*32+31) processes edges beg+h, beg+h+2, ...
// Each lane holds cols [4*(lane&31), +4) as float4. Halves combined at the end
// via shfl_xor(32); lanes 0..31 write the 512 B row.
template <int BIAS, int RELU>
__global__ __launch_bounds__(256) void seg_mean4(
    const float* __restrict__ rows, const int* __restrict__ offs,
    const int* __restrict__ adj, const float* __restrict__ bias,
    float* __restrict__ out, int n_seg) {
  int w = (int)((blockIdx.x * 256 + threadIdx.x) >> 6);
  if (w >= n_seg) return;
  const int lane = threadIdx.x & 63;
  const int half = lane >> 5;
  const int l32 = lane & 31;
  int beg = offs[w], end = offs[w + 1];
  float4 acc = {0.f, 0.f, 0.f, 0.f};
  int j = beg + half;
  for (; j + 2 < end; j += 4) {  // j and j+2 both valid
    int s0 = adj[j], s1 = adj[j + 2];
    float4 v0 = ((const float4*)(rows + (size_t)s0 * DDIM))[l32];
    float4 v1 = ((const float4*)(rows + (size_t)s1 * DDIM))[l32];
    acc.x += v0.x + v1.x;
    acc.y += v0.y + v1.y;
    acc.z += v0.z + v1.z;
    acc.w += v0.w + v1.w;
  }
  if (j < end) {
    int s0 = adj[j];
    float4 v0 = ((const float4*)(rows + (size_t)s0 * DDIM))[l32];
    acc.x += v0.x;
    acc.y += v0.y;
    acc.z += v0.z;
    acc.w += v0.w;
  }
  acc.x += __shfl_xor(acc.x, 32);
  acc.y += __shfl_xor(acc.y, 32);
  acc.z += __shfl_xor(acc.z, 32);
  acc.w += __shfl_xor(acc.w, 32);
  float inv = (end > beg) ? 1.0f / (float)(end - beg) : 0.0f;
  float4 r;
  r.x = acc.x * inv;
  r.y = acc.y * inv;
  r.z = acc.z * inv;
  r.w = acc.w * inv;
  if (BIAS) {
    float4 b = ((const float4*)bias)[l32];
    r.x += b.x; r.y += b.y; r.z += b.z; r.w += b.w;
  }
  if (RELU) {
    r.x = fmaxf(r.x, 0.f);
    r.y = fmaxf(r.y, 0.f);
    r.z = fmaxf(r.z, 0.f);
    r.w = fmaxf(r.w, 0.f);
  }
  if (half == 0) ((float4*)(out + (size_t)w * DDIM))[l32] = r;
}

extern "C" void kernel_launch(void* const* d_in, const int* in_sizes, int n_in,
                              void* d_out, int out_size, void* d_ws, size_t ws_size,
                              hipStream_t stream) {
  const float* x = (const float*)d_in[0];
  const int* eidx = (const int*)d_in[1];
  const float* W1 = (const float*)d_in[2];
  const float* b1 = (const float*)d_in[3];
  const float* W2 = (const float*)d_in[4];
  const float* b2 = (const float*)d_in[5];
  const int nnz = in_sizes[1] / 2;
  const int* src = eidx;
  const int* dst = eidx + nnz;
  float* outf = (float*)d_out;

  char* ws = (char*)d_ws;
  size_t off = 0;
  auto carve = [&](size_t bytes) -> char* {
    char* p = ws + off;
    off += (bytes + 255) & ~(size_t)255;
    return p;
  };
  float* he_raw = (float*)carve((size_t)N_HEDGES * DDIM * 4);  // Binv A_e x
  float* he = (float*)carve((size_t)N_HEDGES * DDIM * 4);      // (Binv A_e x) @ W
  int* degs = (int*)carve((size_t)(N_HEDGES + N_NODES + 128) * 4);  // + partition cursors
  int* deg_e = degs;
  int* deg_n = degs + N_HEDGES;
  int* pcur = degs + N_HEDGES + N_NODES;  // [pcurE(64) | pcurN(64)]
  int* offs_e = (int*)carve((size_t)(N_HEDGES + 1) * 4);
  int* offs_n = (int*)carve((size_t)(N_NODES + 1) * 4);
  int* cur_e = (int*)carve((size_t)N_HEDGES * 4);
  int* cur_n = (int*)carve((size_t)N_NODES * 4);
  int* adj_e = (int*)carve((size_t)nnz * 4);
  int* adj_n = (int*)carve((size_t)nnz * 4);
  int* aux = (int*)carve(64 * 4);
  int2* bktE = (int2*)carve((size_t)64 * BCAP * 8);
  int2* bktN = (int2*)carve((size_t)64 * BCAP * 8);

  hipMemsetAsync(degs, 0, (size_t)(N_HEDGES + N_NODES + 128) * 4, stream);

  const int NB_E = (N_HEDGES + SCAN_BLK_ITEMS - 1) / SCAN_BLK_ITEMS;  // 3
  const int NB_N = (N_NODES + SCAN_BLK_ITEMS - 1) / SCAN_BLK_ITEMS;   // 13
  const int NB_TOT = NB_E + NB_N;                                     // 16

  partition_hist<<<1024, 256, 0, stream>>>(src, dst, nnz, degs, bktE, bktN);
  scan_pass1<<<NB_TOT, 256, 0, stream>>>(deg_e, deg_n, aux, NB_E);
  scan_pass2<<<1, 64, 0, stream>>>(aux, NB_E, NB_TOT, offs_e, offs_n, N_HEDGES, N_NODES);
  scan_pass3<<<NB_TOT, 256, 0, stream>>>(deg_e, deg_n, aux, NB_E, offs_e, offs_n, cur_e, cur_n);
  fill_b<<<16 * FILL_SUB, 256, 0, stream>>>(pcur, bktE, bktN, cur_e, cur_n, adj_e, adj_n);

  // Linear-operator commutation: A_e (X W) == (A_e X) W -> GEMM at the
  // narrowest point (10000 rows instead of 50000).
  // ---- layer 1: h = relu(Dinv A_n ((Binv A_e x) W1) + b1) -> d_out ----
  seg_mean4<0, 0><<<(N_HEDGES + 3) / 4, 256, 0, stream>>>(x, offs_e, adj_e, nullptr, he_raw, N_HEDGES);
  gemm128<<<(N_HEDGES + 31) / 32, 256, 0, stream>>>(he_raw, W1, he, N_HEDGES);
  seg_mean4<1, 1><<<(N_NODES + 3) / 4, 256, 0, stream>>>(he, offs_n, adj_n, b1, outf, N_NODES);

  // ---- layer 2: out = Dinv A_n ((Binv A_e h) W2) + b2 ----
  seg_mean4<0, 0><<<(N_HEDGES + 3) / 4, 256, 0, stream>>>(outf, offs_e, adj_e, nullptr, he_raw, N_HEDGES);
  gemm128<<<(N_HEDGES + 31) / 32, 256, 0, stream>>>(he_raw, W2, he, N_HEDGES);
  seg_mean4<1, 0><<<(N_NODES + 3) / 4, 256, 0, stream>>>(he, offs_n, adj_n, b2, outf, N_NODES);
}

// Round 7
// 392.909 us; speedup vs baseline: 1.9215x; 1.9215x over previous
//
#include <hip/hip_runtime.h>

#define N_NODES 50000
#define N_HEDGES 10000
#define DDIM 128

#define SCAN_BLK_ITEMS 4096  // 256 threads * 16 items
#define NXCD 8

// ---------------- degree histogram, XCD-range-partitioned ----------------
// Block group g = blockIdx&7 (round-robin XCD heuristic) owns
// deg_e[g*1250 .. +1250) and deg_n[g*6250 .. +6250). Each group streams the
// whole edge list and commits only its range -> all atomics to a given cache
// line come from one XCD (L2-local, no cross-XCD ping-pong).
__global__ __launch_bounds__(256) void hist_deg_grp(
    const int* __restrict__ src, const int* __restrict__ dst, int nnz,
    int* __restrict__ deg_e, int* __restrict__ deg_n) {
  const int g = blockIdx.x & (NXCD - 1);
  const int bg = blockIdx.x >> 3;
  const int bpg = gridDim.x >> 3;
  const int e_lo = g * (N_HEDGES / NXCD), e_hi = e_lo + N_HEDGES / NXCD;
  const int n_lo = g * (N_NODES / NXCD), n_hi = n_lo + N_NODES / NXCD;
  const int stride = bpg * 256 * 4;
  for (int i = (bg * 256 + (int)threadIdx.x) * 4; i < nnz; i += stride) {
    if (i + 4 <= nnz) {
      int4 s4 = *(const int4*)(src + i);
      int4 d4 = *(const int4*)(dst + i);
      if (d4.x >= e_lo && d4.x < e_hi) atomicAdd(&deg_e[d4.x], 1);
      if (d4.y >= e_lo && d4.y < e_hi) atomicAdd(&deg_e[d4.y], 1);
      if (d4.z >= e_lo && d4.z < e_hi) atomicAdd(&deg_e[d4.z], 1);
      if (d4.w >= e_lo && d4.w < e_hi) atomicAdd(&deg_e[d4.w], 1);
      if (s4.x >= n_lo && s4.x < n_hi) atomicAdd(&deg_n[s4.x], 1);
      if (s4.y >= n_lo && s4.y < n_hi) atomicAdd(&deg_n[s4.y], 1);
      if (s4.z >= n_lo && s4.z < n_hi) atomicAdd(&deg_n[s4.z], 1);
      if (s4.w >= n_lo && s4.w < n_hi) atomicAdd(&deg_n[s4.w], 1);
    } else {
      for (int j = i; j < nnz; ++j) {
        int d = dst[j], s = src[j];
        if (d >= e_lo && d < e_hi) atomicAdd(&deg_e[d], 1);
        if (s >= n_lo && s < n_hi) atomicAdd(&deg_n[s], 1);
      }
    }
  }
}

// ---------------- hierarchical scan, pass 1: per-block sums ----------------
__global__ __launch_bounds__(256) void scan_pass1(
    const int* __restrict__ deg_e, const int* __restrict__ deg_n,
    int* __restrict__ aux, int nb_e) {
  int b = blockIdx.x;
  const int* deg;
  int n, chunk;
  if (b < nb_e) { deg = deg_e; n = N_HEDGES; chunk = b; }
  else          { deg = deg_n; n = N_NODES;  chunk = b - nb_e; }
  int base = chunk * SCAN_BLK_ITEMS + threadIdx.x * 16;
  int s = 0;
  if (base + 16 <= n) {
    const int4* p = (const int4*)(deg + base);
#pragma unroll
    for (int i = 0; i < 4; ++i) { int4 v = p[i]; s += v.x + v.y + v.z + v.w; }
  } else {
    for (int i = 0; i < 16; ++i) { int idx = base + i; if (idx < n) s += deg[idx]; }
  }
  __shared__ int red[256];
  red[threadIdx.x] = s;
  __syncthreads();
  for (int o = 128; o > 0; o >>= 1) {
    if (threadIdx.x < o) red[threadIdx.x] += red[threadIdx.x + o];
    __syncthreads();
  }
  if (threadIdx.x == 0) aux[b] = red[0];
}

// ---------------- pass 2: serial exclusive scan of block sums (tiny) --------
__global__ __launch_bounds__(64) void scan_pass2(
    int* __restrict__ aux, int nb_e, int nb_tot,
    int* __restrict__ offs_e, int* __restrict__ offs_n, int n_e, int n_n) {
  if (threadIdx.x == 0) {
    int run = 0;
    for (int i = 0; i < nb_e; ++i) { int v = aux[i]; aux[i] = run; run += v; }
    offs_e[n_e] = run;
    run = 0;
    for (int i = nb_e; i < nb_tot; ++i) { int v = aux[i]; aux[i] = run; run += v; }
    offs_n[n_n] = run;
  }
}

// ---------------- pass 3: per-block exclusive scan + aux offset -------------
__global__ __launch_bounds__(256) void scan_pass3(
    const int* __restrict__ deg_e, const int* __restrict__ deg_n,
    const int* __restrict__ aux, int nb_e,
    int* __restrict__ offs_e, int* __restrict__ offs_n,
    int* __restrict__ cur_e, int* __restrict__ cur_n) {
  int b = blockIdx.x;
  const int* deg;
  int n, chunk;
  int *offs, *cur;
  if (b < nb_e) { deg = deg_e; n = N_HEDGES; chunk = b;        offs = offs_e; cur = cur_e; }
  else          { deg = deg_n; n = N_NODES;  chunk = b - nb_e; offs = offs_n; cur = cur_n; }
  int base = chunk * SCAN_BLK_ITEMS + threadIdx.x * 16;
  int v[16];
  int s = 0;
  bool full = (base + 16 <= n);
  if (full) {
    const int4* p = (const int4*)(deg + base);
#pragma unroll
    for (int i = 0; i < 4; ++i) {
      int4 q = p[i];
      v[4 * i] = q.x; v[4 * i + 1] = q.y; v[4 * i + 2] = q.z; v[4 * i + 3] = q.w;
    }
  } else {
    for (int i = 0; i < 16; ++i) { int idx = base + i; v[i] = (idx < n) ? deg[idx] : 0; }
  }
#pragma unroll
  for (int i = 0; i < 16; ++i) { int t = v[i]; v[i] = s; s += t; }
  __shared__ int red[256];
  int t = threadIdx.x;
  red[t] = s;
  __syncthreads();
  for (int o = 1; o < 256; o <<= 1) {
    int u = (t >= o) ? red[t - o] : 0;
    __syncthreads();
    red[t] += u;
    __syncthreads();
  }
  int pre = (t == 0) ? 0 : red[t - 1];
  pre += aux[b];
  if (full) {
#pragma unroll
    for (int i = 0; i < 16; ++i) v[i] += pre;
    int4* o4 = (int4*)(offs + base);
    int4* c4 = (int4*)(cur + base);
#pragma unroll
    for (int i = 0; i < 4; ++i) {
      int4 q = {v[4 * i], v[4 * i + 1], v[4 * i + 2], v[4 * i + 3]};
      o4[i] = q;
      c4[i] = q;
    }
  } else {
    for (int i = 0; i < 16; ++i) {
      int idx = base + i;
      if (idx < n) { offs[idx] = v[i] + pre; cur[idx] = v[i] + pre; }
    }
  }
}

// ---------------- CSR fill, XCD-range-partitioned ----------------
__global__ __launch_bounds__(256) void fill_csr_grp(
    const int* __restrict__ src, const int* __restrict__ dst, int nnz,
    int* __restrict__ cur_e, int* __restrict__ cur_n,
    int* __restrict__ adj_e, int* __restrict__ adj_n) {
  const int g = blockIdx.x & (NXCD - 1);
  const int bg = blockIdx.x >> 3;
  const int bpg = gridDim.x >> 3;
  const int e_lo = g * (N_HEDGES / NXCD), e_hi = e_lo + N_HEDGES / NXCD;
  const int n_lo = g * (N_NODES / NXCD), n_hi = n_lo + N_NODES / NXCD;
  const int stride = bpg * 256 * 4;
  for (int i = (bg * 256 + (int)threadIdx.x) * 4; i < nnz; i += stride) {
    if (i + 4 <= nnz) {
      int4 s4 = *(const int4*)(src + i);
      int4 d4 = *(const int4*)(dst + i);
      if (d4.x >= e_lo && d4.x < e_hi) adj_e[atomicAdd(&cur_e[d4.x], 1)] = s4.x;
      if (d4.y >= e_lo && d4.y < e_hi) adj_e[atomicAdd(&cur_e[d4.y], 1)] = s4.y;
      if (d4.z >= e_lo && d4.z < e_hi) adj_e[atomicAdd(&cur_e[d4.z], 1)] = s4.z;
      if (d4.w >= e_lo && d4.w < e_hi) adj_e[atomicAdd(&cur_e[d4.w], 1)] = s4.w;
      if (s4.x >= n_lo && s4.x < n_hi) adj_n[atomicAdd(&cur_n[s4.x], 1)] = d4.x;
      if (s4.y >= n_lo && s4.y < n_hi) adj_n[atomicAdd(&cur_n[s4.y], 1)] = d4.y;
      if (s4.z >= n_lo && s4.z < n_hi) adj_n[atomicAdd(&cur_n[s4.z], 1)] = d4.z;
      if (s4.w >= n_lo && s4.w < n_hi) adj_n[atomicAdd(&cur_n[s4.w], 1)] = d4.w;
    } else {
      for (int j = i; j < nnz; ++j) {
        int d = dst[j], s = src[j];
        if (d >= e_lo && d < e_hi) adj_e[atomicAdd(&cur_e[d], 1)] = s;
        if (s >= n_lo && s < n_hi) adj_n[atomicAdd(&cur_n[s], 1)] = d;
      }
    }
  }
}

// ---------------- GEMM: Y[n_rows,128] = X[n_rows,128] * W[128,128] ----------
#define ACC4(accv, xv)                                          \
  accv.x += xv.x * w0.x + xv.y * w1.x + xv.z * w2.x + xv.w * w3.x; \
  accv.y += xv.x * w0.y + xv.y * w1.y + xv.z * w2.y + xv.w * w3.y; \
  accv.z += xv.x * w0.z + xv.y * w1.z + xv.z * w2.z + xv.w * w3.z; \
  accv.w += xv.x * w0.w + xv.y * w1.w + xv.z * w2.w + xv.w * w3.w;

__global__ __launch_bounds__(256, 2) void gemm128(
    const float* __restrict__ X, const float* __restrict__ W,
    float* __restrict__ Y, int n_rows) {
  __shared__ float sW[128 * 128];  // 64 KB
  __shared__ float sX[32 * 128];   // 16 KB
  const int t = threadIdx.x;
  {
    const float4* W4 = (const float4*)W;
    float4* sW4w = (float4*)sW;
#pragma unroll
    for (int i = 0; i < 16; ++i) sW4w[t + 256 * i] = W4[t + 256 * i];
  }
  const int lane = t & 63;
  const int wid = t >> 6;
  const int cg = lane & 31;                          // cols [4cg, 4cg+4)
  const int row_in_blk = wid * 8 + (lane >> 5) * 4;  // 4 rows per thread
  const float4* sW4 = (const float4*)sW;

  for (int base = blockIdx.x * 32; base < n_rows; base += gridDim.x * 32) {
    __syncthreads();
    {
      const float4* X4 = (const float4*)(X + (size_t)base * DDIM);
      float4* sX4 = (float4*)sX;
      int limit4 = min(32, n_rows - base) * 32;
#pragma unroll
      for (int i = 0; i < 4; ++i) {
        int idx = t + 256 * i;
        if (idx < limit4) sX4[idx] = X4[idx];
      }
    }
    __syncthreads();
    float4 acc0 = {0, 0, 0, 0}, acc1 = {0, 0, 0, 0}, acc2 = {0, 0, 0, 0}, acc3 = {0, 0, 0, 0};
    const float4* x0 = (const float4*)(sX + (row_in_blk + 0) * DDIM);
    const float4* x1 = (const float4*)(sX + (row_in_blk + 1) * DDIM);
    const float4* x2 = (const float4*)(sX + (row_in_blk + 2) * DDIM);
    const float4* x3 = (const float4*)(sX + (row_in_blk + 3) * DDIM);
#pragma unroll 8
    for (int k4 = 0; k4 < 32; ++k4) {
      float4 w0 = sW4[(4 * k4 + 0) * 32 + cg];
      float4 w1 = sW4[(4 * k4 + 1) * 32 + cg];
      float4 w2 = sW4[(4 * k4 + 2) * 32 + cg];
      float4 w3 = sW4[(4 * k4 + 3) * 32 + cg];
      float4 xa = x0[k4], xb = x1[k4], xc = x2[k4], xd = x3[k4];
      ACC4(acc0, xa)
      ACC4(acc1, xb)
      ACC4(acc2, xc)
      ACC4(acc3, xd)
    }
    int r = base + row_in_blk;
    if (r + 0 < n_rows) ((float4*)(Y + (size_t)(r + 0) * DDIM))[cg] = acc0;
    if (r + 1 < n_rows) ((float4*)(Y + (size_t)(r + 1) * DDIM))[cg] = acc1;
    if (r + 2 < n_rows) ((float4*)(Y + (size_t)(r + 2) * DDIM))[cg] = acc2;
    if (r + 3 < n_rows) ((float4*)(Y + (size_t)(r + 3) * DDIM))[cg] = acc3;
  }
}

// ---------------- segment mean, float4 half-wave, unroll 4 ------------------
// Half-wave h (lanes h*32..) processes edges beg+h, beg+h+2, ... (step 2).
// Each lane holds cols [4*(lane&31), +4) as float4 -> one 512 B coalesced row
// load per edge. Unroll 4 => 8 row loads in flight per wave (gather-latency
// hiding). Halves combined via shfl_xor(32); lanes 0..31 write the row.
template <int BIAS, int RELU>
__global__ __launch_bounds__(256) void seg_mean4(
    const float* __restrict__ rows, const int* __restrict__ offs,
    const int* __restrict__ adj, const float* __restrict__ bias,
    float* __restrict__ out, int n_seg) {
  int w = (int)((blockIdx.x * 256 + threadIdx.x) >> 6);
  if (w >= n_seg) return;
  const int lane = threadIdx.x & 63;
  const int half = lane >> 5;
  const int l32 = lane & 31;
  int beg = offs[w], end = offs[w + 1];
  float4 acc = {0.f, 0.f, 0.f, 0.f};
  int j = beg + half;
  for (; j + 6 < end; j += 8) {  // j, j+2, j+4, j+6 all valid
    int s0 = adj[j], s1 = adj[j + 2], s2 = adj[j + 4], s3 = adj[j + 6];
    float4 v0 = ((const float4*)(rows + (size_t)s0 * DDIM))[l32];
    float4 v1 = ((const float4*)(rows + (size_t)s1 * DDIM))[l32];
    float4 v2 = ((const float4*)(rows + (size_t)s2 * DDIM))[l32];
    float4 v3 = ((const float4*)(rows + (size_t)s3 * DDIM))[l32];
    acc.x += (v0.x + v1.x) + (v2.x + v3.x);
    acc.y += (v0.y + v1.y) + (v2.y + v3.y);
    acc.z += (v0.z + v1.z) + (v2.z + v3.z);
    acc.w += (v0.w + v1.w) + (v2.w + v3.w);
  }
  for (; j < end; j += 2) {
    int s0 = adj[j];
    float4 v0 = ((const float4*)(rows + (size_t)s0 * DDIM))[l32];
    acc.x += v0.x;
    acc.y += v0.y;
    acc.z += v0.z;
    acc.w += v0.w;
  }
  acc.x += __shfl_xor(acc.x, 32);
  acc.y += __shfl_xor(acc.y, 32);
  acc.z += __shfl_xor(acc.z, 32);
  acc.w += __shfl_xor(acc.w, 32);
  float inv = (end > beg) ? 1.0f / (float)(end - beg) : 0.0f;
  float4 r;
  r.x = acc.x * inv;
  r.y = acc.y * inv;
  r.z = acc.z * inv;
  r.w = acc.w * inv;
  if (BIAS) {
    float4 b = ((const float4*)bias)[l32];
    r.x += b.x; r.y += b.y; r.z += b.z; r.w += b.w;
  }
  if (RELU) {
    r.x = fmaxf(r.x, 0.f);
    r.y = fmaxf(r.y, 0.f);
    r.z = fmaxf(r.z, 0.f);
    r.w = fmaxf(r.w, 0.f);
  }
  if (half == 0) ((float4*)(out + (size_t)w * DDIM))[l32] = r;
}

extern "C" void kernel_launch(void* const* d_in, const int* in_sizes, int n_in,
                              void* d_out, int out_size, void* d_ws, size_t ws_size,
                              hipStream_t stream) {
  const float* x = (const float*)d_in[0];
  const int* eidx = (const int*)d_in[1];
  const float* W1 = (const float*)d_in[2];
  const float* b1 = (const float*)d_in[3];
  const float* W2 = (const float*)d_in[4];
  const float* b2 = (const float*)d_in[5];
  const int nnz = in_sizes[1] / 2;
  const int* src = eidx;
  const int* dst = eidx + nnz;
  float* outf = (float*)d_out;

  char* ws = (char*)d_ws;
  size_t off = 0;
  auto carve = [&](size_t bytes) -> char* {
    char* p = ws + off;
    off += (bytes + 255) & ~(size_t)255;
    return p;
  };
  float* he_raw = (float*)carve((size_t)N_HEDGES * DDIM * 4);  // Binv A_e x
  float* he = (float*)carve((size_t)N_HEDGES * DDIM * 4);      // (Binv A_e x) @ W
  int* deg_e = (int*)carve((size_t)(N_HEDGES + N_NODES) * 4);  // contiguous for one memset
  int* deg_n = deg_e + N_HEDGES;
  int* offs_e = (int*)carve((size_t)(N_HEDGES + 1) * 4);
  int* offs_n = (int*)carve((size_t)(N_NODES + 1) * 4);
  int* cur_e = (int*)carve((size_t)N_HEDGES * 4);
  int* cur_n = (int*)carve((size_t)N_NODES * 4);
  int* adj_e = (int*)carve((size_t)nnz * 4);
  int* adj_n = (int*)carve((size_t)nnz * 4);
  int* aux = (int*)carve(64 * 4);

  hipMemsetAsync(deg_e, 0, (size_t)(N_HEDGES + N_NODES) * 4, stream);

  const int NB_E = (N_HEDGES + SCAN_BLK_ITEMS - 1) / SCAN_BLK_ITEMS;  // 3
  const int NB_N = (N_NODES + SCAN_BLK_ITEMS - 1) / SCAN_BLK_ITEMS;   // 13
  const int NB_TOT = NB_E + NB_N;                                     // 16

  hist_deg_grp<<<1024, 256, 0, stream>>>(src, dst, nnz, deg_e, deg_n);
  scan_pass1<<<NB_TOT, 256, 0, stream>>>(deg_e, deg_n, aux, NB_E);
  scan_pass2<<<1, 64, 0, stream>>>(aux, NB_E, NB_TOT, offs_e, offs_n, N_HEDGES, N_NODES);
  scan_pass3<<<NB_TOT, 256, 0, stream>>>(deg_e, deg_n, aux, NB_E, offs_e, offs_n, cur_e, cur_n);
  fill_csr_grp<<<1024, 256, 0, stream>>>(src, dst, nnz, cur_e, cur_n, adj_e, adj_n);

  // Linear-operator commutation: A_e (X W) == (A_e X) W -> GEMM at the
  // narrowest point (10000 rows instead of 50000).
  // ---- layer 1: h = relu(Dinv A_n ((Binv A_e x) W1) + b1) -> d_out ----
  seg_mean4<0, 0><<<(N_HEDGES + 3) / 4, 256, 0, stream>>>(x, offs_e, adj_e, nullptr, he_raw, N_HEDGES);
  gemm128<<<(N_HEDGES + 31) / 32, 256, 0, stream>>>(he_raw, W1, he, N_HEDGES);
  seg_mean4<1, 1><<<(N_NODES + 3) / 4, 256, 0, stream>>>(he, offs_n, adj_n, b1, outf, N_NODES);

  // ---- layer 2: out = Dinv A_n ((Binv A_e h) W2) + b2 ----
  seg_mean4<0, 0><<<(N_HEDGES + 3) / 4, 256, 0, stream>>>(outf, offs_e, adj_e, nullptr, he_raw, N_HEDGES);
  gemm128<<<(N_HEDGES + 31) / 32, 256, 0, stream>>>(he_raw, W2, he, N_HEDGES);
  seg_mean4<1, 0><<<(N_NODES + 3) / 4, 256, 0, stream>>>(he, offs_n, adj_n, b2, outf, N_NODES);
}

// Round 9
// 376.439 us; speedup vs baseline: 2.0056x; 1.0438x over previous
//
#include <hip/hip_runtime.h>

#define N_NODES 50000
#define N_HEDGES 10000
#define DDIM 128

#define SCAN_BLK_ITEMS 4096  // 256 threads * 16 items
#define NXCD 8

#define PBLOCKS 1024  // partition blocks; chunk = ceil(600000/1024) = 586
#define PCAP 160      // per-bucket cap: mean 73.25, sigma 8.0 -> +11 sigma
#define HSUB 32
#define FSUB 32

// ---------------- partition: block-local LDS bucketing, no global cursors ----
// Each block owns a fixed contiguous edge chunk. Classify into 8 owner buckets
// in LDS (LDS atomics only), then write each bucket as one contiguous burst to
// the block's private region bkt[(og*PBLOCKS+blk)*PCAP ...]. Single writer per
// region -> full-line writebacks, zero global-cursor contention (round-6
// lesson: 9375 same-address global atomics serialized at ~30cy each).
__global__ __launch_bounds__(256) void partition_kernel(
    const int* __restrict__ src, const int* __restrict__ dst, int nnz,
    int2* __restrict__ bktE, int* __restrict__ cntE,
    int2* __restrict__ bktN, int* __restrict__ cntN) {
  __shared__ int2 buf[8 * PCAP];
  __shared__ int cnt[8];
  const int blk = blockIdx.x;
  const int chunk = (nnz + PBLOCKS - 1) / PBLOCKS;
  const int lo = blk * chunk;
  const int hi = min(lo + chunk, nnz);
  // ---- E side: key = dst (hyperedge), payload = src ----
  if (threadIdx.x < 8) cnt[threadIdx.x] = 0;
  __syncthreads();
  for (int i = lo + (int)threadIdx.x; i < hi; i += 256) {
    int d = dst[i], s = src[i];
    int og = d / (N_HEDGES / NXCD);
    int p = atomicAdd(&cnt[og], 1);
    if (p < PCAP) buf[og * PCAP + p] = make_int2(d, s);
  }
  __syncthreads();
  for (int b = 0; b < 8; ++b) {
    int c = min(cnt[b], PCAP);
    for (int j = (int)threadIdx.x; j < c; j += 256)
      bktE[((size_t)(b * PBLOCKS + blk)) * PCAP + j] = buf[b * PCAP + j];
  }
  if (threadIdx.x < 8) cntE[blk * 8 + (int)threadIdx.x] = min(cnt[threadIdx.x], PCAP);
  __syncthreads();
  // ---- N side: key = src (node), payload = dst ----
  if (threadIdx.x < 8) cnt[threadIdx.x] = 0;
  __syncthreads();
  for (int i = lo + (int)threadIdx.x; i < hi; i += 256) {
    int d = dst[i], s = src[i];
    int og = s / (N_NODES / NXCD);
    int p = atomicAdd(&cnt[og], 1);
    if (p < PCAP) buf[og * PCAP + p] = make_int2(s, d);
  }
  __syncthreads();
  for (int b = 0; b < 8; ++b) {
    int c = min(cnt[b], PCAP);
    for (int j = (int)threadIdx.x; j < c; j += 256)
      bktN[((size_t)(b * PBLOCKS + blk)) * PCAP + j] = buf[b * PCAP + j];
  }
  if (threadIdx.x < 8) cntN[blk * 8 + (int)threadIdx.x] = min(cnt[threadIdx.x], PCAP);
}

// ---------------- hist from buckets, owner-XCD-local atomics ----------------
// Block: og = blockIdx&7 (round-robin XCD heuristic), side, sub. One wave per
// cell; deg atomics stay in the owner XCD's L2.
__global__ __launch_bounds__(256) void hist_local(
    const int* __restrict__ cntE, const int2* __restrict__ bktE,
    const int* __restrict__ cntN, const int2* __restrict__ bktN,
    int* __restrict__ deg_e, int* __restrict__ deg_n) {
  const int og = blockIdx.x & 7;
  const int side = (blockIdx.x >> 3) & 1;
  const int sub = blockIdx.x >> 4;
  const int* cnt = side ? cntN : cntE;
  const int2* bkt = side ? bktN : bktE;
  int* deg = side ? deg_n : deg_e;
  const int wid = threadIdx.x >> 6;
  const int lane = threadIdx.x & 63;
  for (int blk = sub * 4 + wid; blk < PBLOCKS; blk += HSUB * 4) {
    int c = cnt[blk * 8 + og];
    const int2* p = bkt + ((size_t)(og * PBLOCKS + blk)) * PCAP;
    for (int j = lane; j < c; j += 64) atomicAdd(&deg[p[j].x], 1);
  }
}

// ---------------- hierarchical scan, pass 1: per-block sums ----------------
__global__ __launch_bounds__(256) void scan_pass1(
    const int* __restrict__ deg_e, const int* __restrict__ deg_n,
    int* __restrict__ aux, int nb_e) {
  int b = blockIdx.x;
  const int* deg;
  int n, chunk;
  if (b < nb_e) { deg = deg_e; n = N_HEDGES; chunk = b; }
  else          { deg = deg_n; n = N_NODES;  chunk = b - nb_e; }
  int base = chunk * SCAN_BLK_ITEMS + threadIdx.x * 16;
  int s = 0;
  if (base + 16 <= n) {
    const int4* p = (const int4*)(deg + base);
#pragma unroll
    for (int i = 0; i < 4; ++i) { int4 v = p[i]; s += v.x + v.y + v.z + v.w; }
  } else {
    for (int i = 0; i < 16; ++i) { int idx = base + i; if (idx < n) s += deg[idx]; }
  }
  __shared__ int red[256];
  red[threadIdx.x] = s;
  __syncthreads();
  for (int o = 128; o > 0; o >>= 1) {
    if (threadIdx.x < o) red[threadIdx.x] += red[threadIdx.x + o];
    __syncthreads();
  }
  if (threadIdx.x == 0) aux[b] = red[0];
}

// ---------------- pass 2: serial exclusive scan of block sums (tiny) --------
__global__ __launch_bounds__(64) void scan_pass2(
    int* __restrict__ aux, int nb_e, int nb_tot,
    int* __restrict__ offs_e, int* __restrict__ offs_n, int n_e, int n_n) {
  if (threadIdx.x == 0) {
    int run = 0;
    for (int i = 0; i < nb_e; ++i) { int v = aux[i]; aux[i] = run; run += v; }
    offs_e[n_e] = run;
    run = 0;
    for (int i = nb_e; i < nb_tot; ++i) { int v = aux[i]; aux[i] = run; run += v; }
    offs_n[n_n] = run;
  }
}

// ---------------- pass 3: per-block exclusive scan + aux offset -------------
__global__ __launch_bounds__(256) void scan_pass3(
    const int* __restrict__ deg_e, const int* __restrict__ deg_n,
    const int* __restrict__ aux, int nb_e,
    int* __restrict__ offs_e, int* __restrict__ offs_n,
    int* __restrict__ cur_e, int* __restrict__ cur_n) {
  int b = blockIdx.x;
  const int* deg;
  int n, chunk;
  int *offs, *cur;
  if (b < nb_e) { deg = deg_e; n = N_HEDGES; chunk = b;        offs = offs_e; cur = cur_e; }
  else          { deg = deg_n; n = N_NODES;  chunk = b - nb_e; offs = offs_n; cur = cur_n; }
  int base = chunk * SCAN_BLK_ITEMS + threadIdx.x * 16;
  int v[16];
  int s = 0;
  bool full = (base + 16 <= n);
  if (full) {
    const int4* p = (const int4*)(deg + base);
#pragma unroll
    for (int i = 0; i < 4; ++i) {
      int4 q = p[i];
      v[4 * i] = q.x; v[4 * i + 1] = q.y; v[4 * i + 2] = q.z; v[4 * i + 3] = q.w;
    }
  } else {
    for (int i = 0; i < 16; ++i) { int idx = base + i; v[i] = (idx < n) ? deg[idx] : 0; }
  }
#pragma unroll
  for (int i = 0; i < 16; ++i) { int t = v[i]; v[i] = s; s += t; }
  __shared__ int red[256];
  int t = threadIdx.x;
  red[t] = s;
  __syncthreads();
  for (int o = 1; o < 256; o <<= 1) {
    int u = (t >= o) ? red[t - o] : 0;
    __syncthreads();
    red[t] += u;
    __syncthreads();
  }
  int pre = (t == 0) ? 0 : red[t - 1];
  pre += aux[b];
  if (full) {
#pragma unroll
    for (int i = 0; i < 16; ++i) v[i] += pre;
    int4* o4 = (int4*)(offs + base);
    int4* c4 = (int4*)(cur + base);
#pragma unroll
    for (int i = 0; i < 4; ++i) {
      int4 q = {v[4 * i], v[4 * i + 1], v[4 * i + 2], v[4 * i + 3]};
      o4[i] = q;
      c4[i] = q;
    }
  } else {
    for (int i = 0; i < 16; ++i) {
      int idx = base + i;
      if (idx < n) { offs[idx] = v[i] + pre; cur[idx] = v[i] + pre; }
    }
  }
}

// ---------------- CSR fill from buckets, owner-XCD-local --------------------
// Owner og's cells + its adj/cursor slices all fit that XCD's 4 MB L2; no
// competing stream -> scattered adj writes coalesce into full lines.
__global__ __launch_bounds__(256) void fill_local(
    const int* __restrict__ cntE, const int2* __restrict__ bktE,
    const int* __restrict__ cntN, const int2* __restrict__ bktN,
    int* __restrict__ cur_e, int* __restrict__ cur_n,
    int* __restrict__ adj_e, int* __restrict__ adj_n) {
  const int og = blockIdx.x & 7;
  const int side = (blockIdx.x >> 3) & 1;
  const int sub = blockIdx.x >> 4;
  const int* cnt = side ? cntN : cntE;
  const int2* bkt = side ? bktN : bktE;
  int* cur = side ? cur_n : cur_e;
  int* adj = side ? adj_n : adj_e;
  const int wid = threadIdx.x >> 6;
  const int lane = threadIdx.x & 63;
  for (int blk = sub * 4 + wid; blk < PBLOCKS; blk += FSUB * 4) {
    int c = cnt[blk * 8 + og];
    const int2* p = bkt + ((size_t)(og * PBLOCKS + blk)) * PCAP;
    for (int j = lane; j < c; j += 64) {
      int2 e = p[j];
      adj[atomicAdd(&cur[e.x], 1)] = e.y;
    }
  }
}

// ---------------- GEMM: Y[n_rows,128] = X[n_rows,128] * W[128,128] ----------
#define ACC4(accv, xv)                                          \
  accv.x += xv.x * w0.x + xv.y * w1.x + xv.z * w2.x + xv.w * w3.x; \
  accv.y += xv.x * w0.y + xv.y * w1.y + xv.z * w2.y + xv.w * w3.y; \
  accv.z += xv.x * w0.z + xv.y * w1.z + xv.z * w2.z + xv.w * w3.z; \
  accv.w += xv.x * w0.w + xv.y * w1.w + xv.z * w2.w + xv.w * w3.w;

__global__ __launch_bounds__(256, 2) void gemm128(
    const float* __restrict__ X, const float* __restrict__ W,
    float* __restrict__ Y, int n_rows) {
  __shared__ float sW[128 * 128];  // 64 KB
  __shared__ float sX[32 * 128];   // 16 KB
  const int t = threadIdx.x;
  {
    const float4* W4 = (const float4*)W;
    float4* sW4w = (float4*)sW;
#pragma unroll
    for (int i = 0; i < 16; ++i) sW4w[t + 256 * i] = W4[t + 256 * i];
  }
  const int lane = t & 63;
  const int wid = t >> 6;
  const int cg = lane & 31;                          // cols [4cg, 4cg+4)
  const int row_in_blk = wid * 8 + (lane >> 5) * 4;  // 4 rows per thread
  const float4* sW4 = (const float4*)sW;

  for (int base = blockIdx.x * 32; base < n_rows; base += gridDim.x * 32) {
    __syncthreads();
    {
      const float4* X4 = (const float4*)(X + (size_t)base * DDIM);
      float4* sX4 = (float4*)sX;
      int limit4 = min(32, n_rows - base) * 32;
#pragma unroll
      for (int i = 0; i < 4; ++i) {
        int idx = t + 256 * i;
        if (idx < limit4) sX4[idx] = X4[idx];
      }
    }
    __syncthreads();
    float4 acc0 = {0, 0, 0, 0}, acc1 = {0, 0, 0, 0}, acc2 = {0, 0, 0, 0}, acc3 = {0, 0, 0, 0};
    const float4* x0 = (const float4*)(sX + (row_in_blk + 0) * DDIM);
    const float4* x1 = (const float4*)(sX + (row_in_blk + 1) * DDIM);
    const float4* x2 = (const float4*)(sX + (row_in_blk + 2) * DDIM);
    const float4* x3 = (const float4*)(sX + (row_in_blk + 3) * DDIM);
#pragma unroll 8
    for (int k4 = 0; k4 < 32; ++k4) {
      float4 w0 = sW4[(4 * k4 + 0) * 32 + cg];
      float4 w1 = sW4[(4 * k4 + 1) * 32 + cg];
      float4 w2 = sW4[(4 * k4 + 2) * 32 + cg];
      float4 w3 = sW4[(4 * k4 + 3) * 32 + cg];
      float4 xa = x0[k4], xb = x1[k4], xc = x2[k4], xd = x3[k4];
      ACC4(acc0, xa)
      ACC4(acc1, xb)
      ACC4(acc2, xc)
      ACC4(acc3, xd)
    }
    int r = base + row_in_blk;
    if (r + 0 < n_rows) ((float4*)(Y + (size_t)(r + 0) * DDIM))[cg] = acc0;
    if (r + 1 < n_rows) ((float4*)(Y + (size_t)(r + 1) * DDIM))[cg] = acc1;
    if (r + 2 < n_rows) ((float4*)(Y + (size_t)(r + 2) * DDIM))[cg] = acc2;
    if (r + 3 < n_rows) ((float4*)(Y + (size_t)(r + 3) * DDIM))[cg] = acc3;
  }
}

// ---------------- segment mean, float4 half-wave, unroll 4 ------------------
template <int BIAS, int RELU>
__global__ __launch_bounds__(256) void seg_mean4(
    const float* __restrict__ rows, const int* __restrict__ offs,
    const int* __restrict__ adj, const float* __restrict__ bias,
    float* __restrict__ out, int n_seg) {
  int w = (int)((blockIdx.x * 256 + threadIdx.x) >> 6);
  if (w >= n_seg) return;
  const int lane = threadIdx.x & 63;
  const int half = lane >> 5;
  const int l32 = lane & 31;
  int beg = offs[w], end = offs[w + 1];
  float4 acc = {0.f, 0.f, 0.f, 0.f};
  int j = beg + half;
  for (; j + 6 < end; j += 8) {  // j, j+2, j+4, j+6 all valid
    int s0 = adj[j], s1 = adj[j + 2], s2 = adj[j + 4], s3 = adj[j + 6];
    float4 v0 = ((const float4*)(rows + (size_t)s0 * DDIM))[l32];
    float4 v1 = ((const float4*)(rows + (size_t)s1 * DDIM))[l32];
    float4 v2 = ((const float4*)(rows + (size_t)s2 * DDIM))[l32];
    float4 v3 = ((const float4*)(rows + (size_t)s3 * DDIM))[l32];
    acc.x += (v0.x + v1.x) + (v2.x + v3.x);
    acc.y += (v0.y + v1.y) + (v2.y + v3.y);
    acc.z += (v0.z + v1.z) + (v2.z + v3.z);
    acc.w += (v0.w + v1.w) + (v2.w + v3.w);
  }
  for (; j < end; j += 2) {
    int s0 = adj[j];
    float4 v0 = ((const float4*)(rows + (size_t)s0 * DDIM))[l32];
    acc.x += v0.x;
    acc.y += v0.y;
    acc.z += v0.z;
    acc.w += v0.w;
  }
  acc.x += __shfl_xor(acc.x, 32);
  acc.y += __shfl_xor(acc.y, 32);
  acc.z += __shfl_xor(acc.z, 32);
  acc.w += __shfl_xor(acc.w, 32);
  float inv = (end > beg) ? 1.0f / (float)(end - beg) : 0.0f;
  float4 r;
  r.x = acc.x * inv;
  r.y = acc.y * inv;
  r.z = acc.z * inv;
  r.w = acc.w * inv;
  if (BIAS) {
    float4 b = ((const float4*)bias)[l32];
    r.x += b.x; r.y += b.y; r.z += b.z; r.w += b.w;
  }
  if (RELU) {
    r.x = fmaxf(r.x, 0.f);
    r.y = fmaxf(r.y, 0.f);
    r.z = fmaxf(r.z, 0.f);
    r.w = fmaxf(r.w, 0.f);
  }
  if (half == 0) ((float4*)(out + (size_t)w * DDIM))[l32] = r;
}

extern "C" void kernel_launch(void* const* d_in, const int* in_sizes, int n_in,
                              void* d_out, int out_size, void* d_ws, size_t ws_size,
                              hipStream_t stream) {
  const float* x = (const float*)d_in[0];
  const int* eidx = (const int*)d_in[1];
  const float* W1 = (const float*)d_in[2];
  const float* b1 = (const float*)d_in[3];
  const float* W2 = (const float*)d_in[4];
  const float* b2 = (const float*)d_in[5];
  const int nnz = in_sizes[1] / 2;
  const int* src = eidx;
  const int* dst = eidx + nnz;
  float* outf = (float*)d_out;

  char* ws = (char*)d_ws;
  size_t off = 0;
  auto carve = [&](size_t bytes) -> char* {
    char* p = ws + off;
    off += (bytes + 255) & ~(size_t)255;
    return p;
  };
  float* he_raw = (float*)carve((size_t)N_HEDGES * DDIM * 4);  // Binv A_e x
  float* he = (float*)carve((size_t)N_HEDGES * DDIM * 4);      // (Binv A_e x) @ W
  int* deg_e = (int*)carve((size_t)(N_HEDGES + N_NODES) * 4);  // contiguous for one memset
  int* deg_n = deg_e + N_HEDGES;
  int* offs_e = (int*)carve((size_t)(N_HEDGES + 1) * 4);
  int* offs_n = (int*)carve((size_t)(N_NODES + 1) * 4);
  int* cur_e = (int*)carve((size_t)N_HEDGES * 4);
  int* cur_n = (int*)carve((size_t)N_NODES * 4);
  int* adj_e = (int*)carve((size_t)nnz * 4);
  int* adj_n = (int*)carve((size_t)nnz * 4);
  int* aux = (int*)carve(64 * 4);
  int2* bktE = (int2*)carve((size_t)8 * PBLOCKS * PCAP * 8);
  int2* bktN = (int2*)carve((size_t)8 * PBLOCKS * PCAP * 8);
  int* cntE = (int*)carve((size_t)PBLOCKS * 8 * 4);
  int* cntN = (int*)carve((size_t)PBLOCKS * 8 * 4);

  hipMemsetAsync(deg_e, 0, (size_t)(N_HEDGES + N_NODES) * 4, stream);

  const int NB_E = (N_HEDGES + SCAN_BLK_ITEMS - 1) / SCAN_BLK_ITEMS;  // 3
  const int NB_N = (N_NODES + SCAN_BLK_ITEMS - 1) / SCAN_BLK_ITEMS;   // 13
  const int NB_TOT = NB_E + NB_N;                                     // 16

  partition_kernel<<<PBLOCKS, 256, 0, stream>>>(src, dst, nnz, bktE, cntE, bktN, cntN);
  hist_local<<<16 * HSUB, 256, 0, stream>>>(cntE, bktE, cntN, bktN, deg_e, deg_n);
  scan_pass1<<<NB_TOT, 256, 0, stream>>>(deg_e, deg_n, aux, NB_E);
  scan_pass2<<<1, 64, 0, stream>>>(aux, NB_E, NB_TOT, offs_e, offs_n, N_HEDGES, N_NODES);
  scan_pass3<<<NB_TOT, 256, 0, stream>>>(deg_e, deg_n, aux, NB_E, offs_e, offs_n, cur_e, cur_n);
  fill_local<<<16 * FSUB, 256, 0, stream>>>(cntE, bktE, cntN, bktN, cur_e, cur_n, adj_e, adj_n);

  // Linear-operator commutation: A_e (X W) == (A_e X) W -> GEMM at the
  // narrowest point (10000 rows instead of 50000).
  // ---- layer 1: h = relu(Dinv A_n ((Binv A_e x) W1) + b1) -> d_out ----
  seg_mean4<0, 0><<<(N_HEDGES + 3) / 4, 256, 0, stream>>>(x, offs_e, adj_e, nullptr, he_raw, N_HEDGES);
  gemm128<<<(N_HEDGES + 31) / 32, 256, 0, stream>>>(he_raw, W1, he, N_HEDGES);
  seg_mean4<1, 1><<<(N_NODES + 3) / 4, 256, 0, stream>>>(he, offs_n, adj_n, b1, outf, N_NODES);

  // ---- layer 2: out = Dinv A_n ((Binv A_e h) W2) + b2 ----
  seg_mean4<0, 0><<<(N_HEDGES + 3) / 4, 256, 0, stream>>>(outf, offs_e, adj_e, nullptr, he_raw, N_HEDGES);
  gemm128<<<(N_HEDGES + 31) / 32, 256, 0, stream>>>(he_raw, W2, he, N_HEDGES);
  seg_mean4<1, 0><<<(N_NODES + 3) / 4, 256, 0, stream>>>(he, offs_n, adj_n, b2, outf, N_NODES);
}